// Round 1
// baseline (130.416 us; speedup 1.0000x reference)
//
#include <hip/hip_runtime.h>
#include <hip/hip_bf16.h>

#define N_ROWS 8192
#define DIM    128
#define NCHUNK 8            // column chunks in sim kernel
#define CHUNKC (N_ROWS / NCHUNK)

typedef __attribute__((ext_vector_type(8))) short short8;
typedef __attribute__((ext_vector_type(4))) float f32x4;

__device__ inline unsigned short f2bf(float f) {
    unsigned u = __float_as_uint(f);
    unsigned r = (u + 0x7FFFu + ((u >> 16) & 1u)) >> 16;
    return (unsigned short)r;
}

// Kernel 1: per-row L2 normalize embed -> bf16 (for MFMA), and compute
// e2p[i] = exp(2 * dot(en_i, pn_i)) in fp32.
// 1 wave per row, 4 waves per block.
__global__ __launch_bounds__(256) void norm_kernel(
    const float* __restrict__ embed, const float* __restrict__ proxy,
    short* __restrict__ enb, float* __restrict__ e2p)
{
    int wave = threadIdx.x >> 6, lane = threadIdx.x & 63;
    int row = blockIdx.x * 4 + wave;

    const float2 ev = *(const float2*)(embed + row * DIM + lane * 2);
    float ss = ev.x * ev.x + ev.y * ev.y;
#pragma unroll
    for (int m = 1; m < 64; m <<= 1) ss += __shfl_xor(ss, m, 64);
    float inv_e = 1.0f / fmaxf(sqrtf(ss), 1e-8f);
    float ex = ev.x * inv_e, ey = ev.y * inv_e;

    const float2 pv = *(const float2*)(proxy + row * DIM + lane * 2);
    float ps = pv.x * pv.x + pv.y * pv.y;
#pragma unroll
    for (int m = 1; m < 64; m <<= 1) ps += __shfl_xor(ps, m, 64);
    float inv_p = 1.0f / fmaxf(sqrtf(ps), 1e-8f);

    float dot = ex * (pv.x * inv_p) + ey * (pv.y * inv_p);
#pragma unroll
    for (int m = 1; m < 64; m <<= 1) dot += __shfl_xor(dot, m, 64);

    ushort2 st; st.x = f2bf(ex); st.y = f2bf(ey);
    *(ushort2*)(enb + row * DIM + lane * 2) = st;
    if (lane == 0) e2p[row] = __expf(2.0f * dot);
}

// Kernel 2: fused sim-GEMM + exp + masked row sums.
// Block = 256 threads (4 waves). blockIdx.x: 128 row blocks of 64 rows
// (wave w owns rows rbase+w*16 .. +15). blockIdx.y: 8 column chunks of 1024.
// Each wave: 16x16 output tiles via mfma_f32_16x16x32_bf16, K = 128 = 4x32.
// Accumulate exp(2*sim) into tot/pos per row, excluding diagonal.
__global__ __launch_bounds__(256) void simsum_kernel(
    const short* __restrict__ enb, const int* __restrict__ label,
    float* __restrict__ ptot, float* __restrict__ ppos)
{
    int wave = threadIdx.x >> 6, lane = threadIdx.x & 63;
    int lrow = lane & 15, lk = lane >> 4;
    int rbase = blockIdx.x * 64 + wave * 16;

    // A fragments: lane holds A[row = lrow][k = kk*32 + lk*8 + j]
    short8 a[4];
    const short* arow = enb + (rbase + lrow) * DIM;
#pragma unroll
    for (int kk = 0; kk < 4; kk++)
        a[kk] = *(const short8*)(arow + kk * 32 + lk * 8);

    // this lane's 4 accumulator rows (C layout: row = lk*4 + r, col = lrow)
    int myrow[4], myrlab[4];
#pragma unroll
    for (int r = 0; r < 4; r++) {
        myrow[r] = rbase + lk * 4 + r;
        myrlab[r] = label[myrow[r]];
    }

    float tot[4] = {0.f, 0.f, 0.f, 0.f};
    float pos[4] = {0.f, 0.f, 0.f, 0.f};

    int cbase0 = blockIdx.y * CHUNKC;
    for (int t = 0; t < CHUNKC / 16; t++) {
        int cbase = cbase0 + t * 16;
        // B fragments: for en*en^T, B[k][n] = en[cbase+n][k] -> same load
        // pattern as A with the column's row index.
        const short* brow = enb + (cbase + lrow) * DIM;
        short8 b0 = *(const short8*)(brow + 0 * 32 + lk * 8);
        short8 b1 = *(const short8*)(brow + 1 * 32 + lk * 8);
        short8 b2 = *(const short8*)(brow + 2 * 32 + lk * 8);
        short8 b3 = *(const short8*)(brow + 3 * 32 + lk * 8);

        f32x4 c = {0.f, 0.f, 0.f, 0.f};
        c = __builtin_amdgcn_mfma_f32_16x16x32_bf16(a[0], b0, c, 0, 0, 0);
        c = __builtin_amdgcn_mfma_f32_16x16x32_bf16(a[1], b1, c, 0, 0, 0);
        c = __builtin_amdgcn_mfma_f32_16x16x32_bf16(a[2], b2, c, 0, 0, 0);
        c = __builtin_amdgcn_mfma_f32_16x16x32_bf16(a[3], b3, c, 0, 0, 0);

        int col = cbase + lrow;   // C col for this lane
        int clab = label[col];
#pragma unroll
        for (int r = 0; r < 4; r++) {
            float s = __expf(2.0f * c[r]);
            float sv = (col == myrow[r]) ? 0.f : s;  // remove diagonal
            tot[r] += sv;
            pos[r] += (clab == myrlab[r]) ? sv : 0.f;
        }
    }

    // reduce across the 16 column-lanes (same lk group)
#pragma unroll
    for (int m = 1; m < 16; m <<= 1) {
#pragma unroll
        for (int r = 0; r < 4; r++) {
            tot[r] += __shfl_xor(tot[r], m, 64);
            pos[r] += __shfl_xor(pos[r], m, 64);
        }
    }
    if (lrow == 0) {
#pragma unroll
        for (int r = 0; r < 4; r++) {
            int row = rbase + lk * 4 + r;
            ptot[blockIdx.y * N_ROWS + row] = tot[r];
            ppos[blockIdx.y * N_ROWS + row] = pos[r];
        }
    }
}

// Kernel 3a: per-row log-ratio, block partial sums (32 blocks x 256 threads).
__global__ __launch_bounds__(256) void loss_partial_kernel(
    const float* __restrict__ e2p, const float* __restrict__ ptot,
    const float* __restrict__ ppos, float* __restrict__ pl)
{
    int i = blockIdx.x * 256 + threadIdx.x;
    float tot = 0.f, pos = 0.f;
#pragma unroll
    for (int c = 0; c < NCHUNK; c++) {
        tot += ptot[c * N_ROWS + i];
        pos += ppos[c * N_ROWS + i];
    }
    float e = e2p[i];
    float v = __logf((e + pos) / (e + tot));
#pragma unroll
    for (int m = 1; m < 64; m <<= 1) v += __shfl_xor(v, m, 64);
    __shared__ float red[4];
    int wave = threadIdx.x >> 6, lane = threadIdx.x & 63;
    if (lane == 0) red[wave] = v;
    __syncthreads();
    if (threadIdx.x == 0) pl[blockIdx.x] = red[0] + red[1] + red[2] + red[3];
}

// Kernel 3b: final sum of 32 partials -> -mean
__global__ void loss_final_kernel(const float* __restrict__ pl,
                                  float* __restrict__ out)
{
    float v = (threadIdx.x < 32) ? pl[threadIdx.x] : 0.f;
#pragma unroll
    for (int m = 1; m < 64; m <<= 1) v += __shfl_xor(v, m, 64);
    if (threadIdx.x == 0) out[0] = -v / (float)N_ROWS;
}

extern "C" void kernel_launch(void* const* d_in, const int* in_sizes, int n_in,
                              void* d_out, int out_size, void* d_ws, size_t ws_size,
                              hipStream_t stream) {
    const float* embed = (const float*)d_in[0];
    const float* proxy = (const float*)d_in[1];
    const int*   label = (const int*)d_in[2];
    float* out = (float*)d_out;

    char* ws = (char*)d_ws;
    short* enb = (short*)ws;                                    // 2 MB
    float* e2p = (float*)(ws + 2u * N_ROWS * DIM);              // 32 KB
    float* ptot = e2p + N_ROWS;                                 // 256 KB
    float* ppos = ptot + NCHUNK * N_ROWS;                       // 256 KB
    float* pl   = ppos + NCHUNK * N_ROWS;                       // 128 B

    hipLaunchKernelGGL(norm_kernel, dim3(N_ROWS / 4), dim3(256), 0, stream,
                       embed, proxy, enb, e2p);
    hipLaunchKernelGGL(simsum_kernel, dim3(N_ROWS / 64, NCHUNK), dim3(256), 0, stream,
                       enb, label, ptot, ppos);
    hipLaunchKernelGGL(loss_partial_kernel, dim3(N_ROWS / 256), dim3(256), 0, stream,
                       e2p, ptot, ppos, pl);
    hipLaunchKernelGGL(loss_final_kernel, dim3(1), dim3(64), 0, stream, pl, out);
}

// Round 2
// 80.586 us; speedup vs baseline: 1.6183x; 1.6183x over previous
//
#include <hip/hip_runtime.h>
#include <hip/hip_bf16.h>

#define N_ROWS 8192
#define DIM    128
#define NCHUNK 16                  // column chunks in sim kernel
#define CHUNKC (N_ROWS / NCHUNK)   // 512 cols per chunk

typedef __attribute__((ext_vector_type(8)))  short short8;
typedef __attribute__((ext_vector_type(16))) float f32x16;

__device__ inline unsigned short f2bf(float f) {
    unsigned u = __float_as_uint(f);
    unsigned r = (u + 0x7FFFu + ((u >> 16) & 1u)) >> 16;
    return (unsigned short)r;
}

// Kernel 1: per-row L2 normalize embed -> bf16, and e2p[i] = exp(2*dot(en,pn)).
__global__ __launch_bounds__(256) void norm_kernel(
    const float* __restrict__ embed, const float* __restrict__ proxy,
    short* __restrict__ enb, float* __restrict__ e2p)
{
    int wave = threadIdx.x >> 6, lane = threadIdx.x & 63;
    int row = blockIdx.x * 4 + wave;

    const float2 ev = *(const float2*)(embed + row * DIM + lane * 2);
    float ss = ev.x * ev.x + ev.y * ev.y;
#pragma unroll
    for (int m = 1; m < 64; m <<= 1) ss += __shfl_xor(ss, m, 64);
    float inv_e = 1.0f / fmaxf(sqrtf(ss), 1e-8f);
    float ex = ev.x * inv_e, ey = ev.y * inv_e;

    const float2 pv = *(const float2*)(proxy + row * DIM + lane * 2);
    float ps = pv.x * pv.x + pv.y * pv.y;
#pragma unroll
    for (int m = 1; m < 64; m <<= 1) ps += __shfl_xor(ps, m, 64);
    float inv_p = 1.0f / fmaxf(sqrtf(ps), 1e-8f);

    float dot = ex * (pv.x * inv_p) + ey * (pv.y * inv_p);
#pragma unroll
    for (int m = 1; m < 64; m <<= 1) dot += __shfl_xor(dot, m, 64);

    ushort2 st; st.x = f2bf(ex); st.y = f2bf(ey);
    *(ushort2*)(enb + row * DIM + lane * 2) = st;
    if (lane == 0) e2p[row] = __expf(2.0f * dot);
}

// Kernel 2: fused sim-GEMM (32x32x16 MFMA, register-blocked) + exp + masked
// row sums. Block = 4 waves; wave w owns 32 rows (A resident in regs) and
// sweeps this block's 512-column chunk in 32-col steps.
// C/D layout (m74/m101): col = lane&31, row = (reg&3) + 4*(lane>>5) + 8*(reg>>2).
__global__ __launch_bounds__(256) void simsum_kernel(
    const short* __restrict__ enb, const int* __restrict__ label,
    float* __restrict__ ptot, float* __restrict__ ppos)
{
    const int wave = threadIdx.x >> 6, lane = threadIdx.x & 63;
    const int cl = lane & 31;       // col-lane / row-lane within 32
    const int hi = lane >> 5;       // k-group
    const int wrbase = blockIdx.x * 128 + wave * 32;   // wave's first row

    // A fragments: lane holds A[wrbase + cl][k = kk*16 + hi*8 + j]
    short8 a[8];
    const short* arow = enb + (size_t)(wrbase + cl) * DIM + hi * 8;
#pragma unroll
    for (int kk = 0; kk < 8; kk++)
        a[kk] = *(const short8*)(arow + kk * 16);

    // per-acc-element row offset rr[reg] and its label
    int rlab[16];
#pragma unroll
    for (int reg = 0; reg < 16; reg++) {
        int rr = (reg & 3) + 4 * hi + 8 * (reg >> 2);
        rlab[reg] = label[wrbase + rr];
    }

    float tot[16], pos[16];
#pragma unroll
    for (int reg = 0; reg < 16; reg++) { tot[reg] = 0.f; pos[reg] = 0.f; }

    const int cbase0 = blockIdx.y * CHUNKC;
    for (int t = 0; t < CHUNKC / 32; t++) {
        const int cbase = cbase0 + t * 32;
        const int col = cbase + cl;

        // B fragments: lane holds B[k = kk*16 + hi*8 + j][col]
        const short* brow = enb + (size_t)col * DIM + hi * 8;
        short8 b[8];
#pragma unroll
        for (int kk = 0; kk < 8; kk++)
            b[kk] = *(const short8*)(brow + kk * 16);

        const int clab = label[col];

        f32x16 c = {};
#pragma unroll
        for (int kk = 0; kk < 8; kk++)
            c = __builtin_amdgcn_mfma_f32_32x32x16_bf16(a[kk], b[kk], c, 0, 0, 0);

        if (cbase == wrbase) {
            // diagonal tile: mask out col == row
#pragma unroll
            for (int reg = 0; reg < 16; reg++) {
                int rr = (reg & 3) + 4 * hi + 8 * (reg >> 2);
                float s = __expf(2.0f * c[reg]);
                s = (cl == rr) ? 0.f : s;
                tot[reg] += s;
                pos[reg] += (clab == rlab[reg]) ? s : 0.f;
            }
        } else {
#pragma unroll
            for (int reg = 0; reg < 16; reg++) {
                float s = __expf(2.0f * c[reg]);
                tot[reg] += s;
                pos[reg] += (clab == rlab[reg]) ? s : 0.f;
            }
        }
    }

    // reduce across the 32 column-lanes (xor masks stay within the 32-group)
#pragma unroll
    for (int m = 1; m < 32; m <<= 1) {
#pragma unroll
        for (int reg = 0; reg < 16; reg++) {
            tot[reg] += __shfl_xor(tot[reg], m, 64);
            pos[reg] += __shfl_xor(pos[reg], m, 64);
        }
    }
    if (cl == 0) {
#pragma unroll
        for (int reg = 0; reg < 16; reg++) {
            int row = wrbase + (reg & 3) + 4 * hi + 8 * (reg >> 2);
            ptot[blockIdx.y * N_ROWS + row] = tot[reg];
            ppos[blockIdx.y * N_ROWS + row] = pos[reg];
        }
    }
}

// Kernel 3a: per-row log-ratio, block partial sums.
__global__ __launch_bounds__(256) void loss_partial_kernel(
    const float* __restrict__ e2p, const float* __restrict__ ptot,
    const float* __restrict__ ppos, float* __restrict__ pl)
{
    int i = blockIdx.x * 256 + threadIdx.x;
    float tot = 0.f, pos = 0.f;
#pragma unroll
    for (int c = 0; c < NCHUNK; c++) {
        tot += ptot[c * N_ROWS + i];
        pos += ppos[c * N_ROWS + i];
    }
    float e = e2p[i];
    float v = __logf((e + pos) / (e + tot));
#pragma unroll
    for (int m = 1; m < 64; m <<= 1) v += __shfl_xor(v, m, 64);
    __shared__ float red[4];
    int wave = threadIdx.x >> 6, lane = threadIdx.x & 63;
    if (lane == 0) red[wave] = v;
    __syncthreads();
    if (threadIdx.x == 0) pl[blockIdx.x] = red[0] + red[1] + red[2] + red[3];
}

// Kernel 3b: final sum of 32 partials -> -mean
__global__ void loss_final_kernel(const float* __restrict__ pl,
                                  float* __restrict__ out)
{
    float v = (threadIdx.x < 32) ? pl[threadIdx.x] : 0.f;
#pragma unroll
    for (int m = 1; m < 64; m <<= 1) v += __shfl_xor(v, m, 64);
    if (threadIdx.x == 0) out[0] = -v / (float)N_ROWS;
}

extern "C" void kernel_launch(void* const* d_in, const int* in_sizes, int n_in,
                              void* d_out, int out_size, void* d_ws, size_t ws_size,
                              hipStream_t stream) {
    const float* embed = (const float*)d_in[0];
    const float* proxy = (const float*)d_in[1];
    const int*   label = (const int*)d_in[2];
    float* out = (float*)d_out;

    char* ws = (char*)d_ws;
    short* enb = (short*)ws;                                    // 2 MB
    float* e2p = (float*)(ws + 2u * N_ROWS * DIM);              // 32 KB
    float* ptot = e2p + N_ROWS;                                 // 512 KB
    float* ppos = ptot + NCHUNK * N_ROWS;                       // 512 KB
    float* pl   = ppos + NCHUNK * N_ROWS;                       // 128 B

    hipLaunchKernelGGL(norm_kernel, dim3(N_ROWS / 4), dim3(256), 0, stream,
                       embed, proxy, enb, e2p);
    hipLaunchKernelGGL(simsum_kernel, dim3(N_ROWS / 128, NCHUNK), dim3(256), 0, stream,
                       enb, label, ptot, ppos);
    hipLaunchKernelGGL(loss_partial_kernel, dim3(N_ROWS / 256), dim3(256), 0, stream,
                       e2p, ptot, ppos, pl);
    hipLaunchKernelGGL(loss_final_kernel, dim3(1), dim3(64), 0, stream, pl, out);
}